// Round 10
// baseline (44.771 us; speedup 1.0000x reference)
//
#include <hip/hip_runtime.h>

// ============================================================================
// ROUND 10 = R3 (best: 35.6 µs) + a controlled 2x inner-loop probe.
// The ONLY change vs R3: each staged tile is scanned twice (pass 2 reversed,
// separate accumulator, fmin-combined at the end -> bit-identical output,
// not CSE-able). Purpose: dur_us - 35.6 measures the nn inner loop's true
// share, which 7 rounds of structural changes could not move or attribute.
// ============================================================================

#define TPB   128    // threads per nn block (2 waves)
#define QPT   8      // query points per thread (registers)
#define SPLIT 32     // database slices per direction (4096/32 = 128 = one stage)
#define RTPB  256    // reduction threads per block

// ---------------------------------------------------------------------------
// nn: directed nearest-neighbor min, both directions in one launch.
//   blockIdx.z = 0 : query = pred  (NA=N), DB = target (NB=M), all valid
//   blockIdx.z = 1 : query = target(NA=M), DB = pred   (NB=N), label-mask
// DB staged as (-2x,-2y,-2z,|t|^2); candidate = 3-fma chain; min over it is
// min over d shifted by |p|^2 (added per query at the end, clamped >= 0).
// Invalid/pad DB points: coords=0, tn=1e10 (reference BIG).
// ---------------------------------------------------------------------------
__global__ void __launch_bounds__(TPB) nn_kernel(
    const float* __restrict__ pred,
    const float* __restrict__ target,
    const int*   __restrict__ label,
    float* __restrict__ minsplit,     // [2][B][SPLIT][stride]
    int B, int N, int M, int natmax, int stride)
{
    __shared__ float4 tile[TPB];

    const int dir = blockIdx.z;
    const float* __restrict__ A  = dir ? target : pred;
    const float* __restrict__ Bp = dir ? pred   : target;
    const int NA = dir ? M : N;
    const int NB = dir ? N : M;
    const int* __restrict__ labB = dir ? label : nullptr;

    const int natiles = (NA + TPB * QPT - 1) / (TPB * QPT);
    const int b  = blockIdx.x / natmax;
    const int at = blockIdx.x - b * natmax;
    if (at >= natiles) return;

    const size_t abase = (size_t)b * NA;

    float px[QPT], py[QPT], pz[QPT], pn[QPT], best[QPT], best2[QPT];
#pragma unroll
    for (int q = 0; q < QPT; ++q) {
        int a = at * (TPB * QPT) + q * TPB + threadIdx.x;
        int idx = (a < NA) ? a : 0;
        const float* sp = A + (abase + idx) * 3;
        px[q] = sp[0];
        py[q] = sp[1];
        pz[q] = sp[2];
        pn[q] = fmaf(px[q], px[q], fmaf(py[q], py[q], pz[q] * pz[q]));
        best[q]  = 3.0e38f;
        best2[q] = 3.0e38f;
    }

    const int slen = (NB + SPLIT - 1) / SPLIT;
    const int sbeg = blockIdx.y * slen;
    const int send = min(sbeg + slen, NB);
    const size_t bbase = (size_t)b * NB;

    for (int c = sbeg; c < send; c += TPB) {
        int m = c + threadIdx.x;
        float4 qv = make_float4(0.0f, 0.0f, 0.0f, 1.0e10f);  // pad sentinel
        if (m < send) {
            const float* sp = Bp + (bbase + m) * 3;
            float x = sp[0], y = sp[1], z = sp[2];
            float tn = fmaf(x, x, fmaf(y, y, z * z));
            if (labB != nullptr && labB[bbase + m] != 1) {    // invalid point
                x = 0.0f; y = 0.0f; z = 0.0f; tn = 1.0e10f;
            }
            qv = make_float4(-2.0f * x, -2.0f * y, -2.0f * z, tn);
        }
        __syncthreads();              // protect previous iteration's reads
        tile[threadIdx.x] = qv;
        __syncthreads();

        const int jn = min(send - c, TPB);
        const int jeven = jn & ~1;

        // ---- pass 1: forward ----
#pragma unroll 8
        for (int j = 0; j < jeven; j += 2) {
            float4 t0 = tile[j];      // wave-uniform -> LDS broadcast
            float4 t1 = tile[j + 1];
#pragma unroll
            for (int q = 0; q < QPT; ++q) {
                float v0 = fmaf(px[q], t0.x, fmaf(py[q], t0.y, fmaf(pz[q], t0.z, t0.w)));
                float v1 = fmaf(px[q], t1.x, fmaf(py[q], t1.y, fmaf(pz[q], t1.z, t1.w)));
                best[q] = fminf(best[q], fminf(v0, v1));   // -> v_min3_f32
            }
        }
        if (jn & 1) {
            float4 t0 = tile[jn - 1];
#pragma unroll
            for (int q = 0; q < QPT; ++q) {
                float v0 = fmaf(px[q], t0.x, fmaf(py[q], t0.y, fmaf(pz[q], t0.z, t0.w)));
                best[q] = fminf(best[q], v0);
            }
        }

        // ---- pass 2: PROBE — same tile, reverse order, separate acc.
        // Result is bit-identical (same min set, no NaN); reverse order +
        // separate accumulator prevent CSE, so this is a pure 2x-work probe.
#pragma unroll 8
        for (int j = jeven - 2; j >= 0; j -= 2) {
            float4 t0 = tile[j];
            float4 t1 = tile[j + 1];
#pragma unroll
            for (int q = 0; q < QPT; ++q) {
                float v0 = fmaf(px[q], t0.x, fmaf(py[q], t0.y, fmaf(pz[q], t0.z, t0.w)));
                float v1 = fmaf(px[q], t1.x, fmaf(py[q], t1.y, fmaf(pz[q], t1.z, t1.w)));
                best2[q] = fminf(best2[q], fminf(v0, v1));
            }
        }
        if (jn & 1) {
            float4 t0 = tile[jn - 1];
#pragma unroll
            for (int q = 0; q < QPT; ++q) {
                float v0 = fmaf(px[q], t0.x, fmaf(py[q], t0.y, fmaf(pz[q], t0.z, t0.w)));
                best2[q] = fminf(best2[q], v0);
            }
        }
    }

    float* out = minsplit + (((size_t)dir * B + b) * SPLIT + blockIdx.y) * stride;
#pragma unroll
    for (int q = 0; q < QPT; ++q) {
        int a = at * (TPB * QPT) + q * TPB + threadIdx.x;
        if (a < NA) {
            out[a] = fmaxf(fminf(best[q], best2[q]) + pn[q], 0.0f);
        }
    }
}

// ---------------------------------------------------------------------------
// Stage A: per-query min over SPLIT slices, sqrt, masked block-level sums.
// One partial triple per block, fixed-order reduction -> deterministic.
// (verbatim R3)
// ---------------------------------------------------------------------------
__device__ float block_reduce_sum(float v, float* red) {
    int tid = threadIdx.x;
    red[tid] = v;
    __syncthreads();
    for (int s = RTPB / 2; s > 0; s >>= 1) {
        if (tid < s) red[tid] += red[tid + s];
        __syncthreads();
    }
    float r = red[0];
    __syncthreads();
    return r;
}

__global__ void __launch_bounds__(RTPB) partial_kernel(
    const float* __restrict__ minsplit,
    const int* __restrict__ label,
    float* __restrict__ s1, float* __restrict__ c1, float* __restrict__ s2,
    int B, int N, int M, int ptN, int ptM, int stride)
{
    __shared__ float red[RTPB];
    const int r = blockIdx.x;
    const int regionN = B * ptN;

    if (r < regionN) {                       // dir 0: pred -> target (masked)
        int b = r / ptN;
        int t = r - b * ptN;
        int n = t * RTPB + threadIdx.x;
        float s = 0.0f, cc = 0.0f;
        if (n < N) {
            const float* base = minsplit + ((size_t)b * SPLIT) * stride + n;
            float m = base[0];
            for (int sp = 1; sp < SPLIT; ++sp) {
                m = fminf(m, base[(size_t)sp * stride]);
            }
            if (label[(size_t)b * N + n] == 1) {
                s = sqrtf(m);
                cc = 1.0f;
            }
        }
        s  = block_reduce_sum(s, red);
        cc = block_reduce_sum(cc, red);
        if (threadIdx.x == 0) { s1[r] = s; c1[r] = cc; }
    } else {                                 // dir 1: target -> pred (mean)
        int r2 = r - regionN;
        int b = r2 / ptM;
        int t = r2 - b * ptM;
        int mq = t * RTPB + threadIdx.x;
        float s = 0.0f;
        if (mq < M) {
            const float* base = minsplit + (((size_t)B + b) * SPLIT) * stride + mq;
            float m = base[0];
            for (int sp = 1; sp < SPLIT; ++sp) {
                m = fminf(m, base[(size_t)sp * stride]);
            }
            s = sqrtf(m);
        }
        s = block_reduce_sum(s, red);
        if (threadIdx.x == 0) s2[r2] = s;
    }
}

// ---------------------------------------------------------------------------
// Stage B: tiny deterministic final combine (one block, 64 threads).
// (verbatim R3)
// ---------------------------------------------------------------------------
__global__ void __launch_bounds__(64) final_kernel(
    const float* __restrict__ s1, const float* __restrict__ c1,
    const float* __restrict__ s2,
    float* __restrict__ out, int B, int M, int ptN, int ptM)
{
    __shared__ float acc[64];
    int tid = threadIdx.x;
    float v = 0.0f;
    if (tid < B) {
        float S1 = 0.0f, C1 = 0.0f, S2 = 0.0f;
        for (int i = 0; i < ptN; ++i) { S1 += s1[tid * ptN + i]; C1 += c1[tid * ptN + i]; }
        for (int i = 0; i < ptM; ++i) { S2 += s2[tid * ptM + i]; }
        float m1 = S1 / fmaxf(C1, 1.0f);
        float m2 = S2 / (float)M;
        v = 0.5f * (m1 + m2);
    }
    acc[tid] = v;
    __syncthreads();
    if (tid == 0) {
        float a = 0.0f;
        for (int b = 0; b < B; ++b) a += acc[b];
        out[0] = a / (float)B;   // * LOSS_WEIGHT (== 1.0)
    }
}

// ---------------------------------------------------------------------------
extern "C" void kernel_launch(void* const* d_in, const int* in_sizes, int n_in,
                              void* d_out, int out_size, void* d_ws, size_t ws_size,
                              hipStream_t stream) {
    const float* pred   = (const float*)d_in[0];  // B*N*3 f32
    const float* target = (const float*)d_in[1];  // B*M*3 f32
    const int*   label  = (const int*)  d_in[2];  // B*N   i32

    const int B = in_sizes[3];                 // nums has shape (B,)
    const int N = in_sizes[2] / B;             // label is B*N
    const int M = in_sizes[1] / (3 * B);       // target is B*M*3

    const int stride = (N > M) ? N : M;

    // workspace layout (~4.2 MiB of the provided scratch)
    float* minsplit = (float*)d_ws;                              // 2*B*SPLIT*stride
    const int ptN = (N + RTPB - 1) / RTPB;
    const int ptM = (M + RTPB - 1) / RTPB;
    float* s1 = minsplit + (size_t)2 * B * SPLIT * stride;       // B*ptN
    float* c1 = s1 + (size_t)B * ptN;                            // B*ptN
    float* s2 = c1 + (size_t)B * ptN;                            // B*ptM

    const int nat1 = (N + TPB * QPT - 1) / (TPB * QPT);
    const int nat2 = (M + TPB * QPT - 1) / (TPB * QPT);
    const int natmax = (nat1 > nat2) ? nat1 : nat2;
    dim3 g(B * natmax, SPLIT, 2);
    nn_kernel<<<g, TPB, 0, stream>>>(pred, target, label, minsplit,
                                     B, N, M, natmax, stride);

    const int nred = B * (ptN + ptM);
    partial_kernel<<<nred, RTPB, 0, stream>>>(minsplit, label, s1, c1, s2,
                                              B, N, M, ptN, ptM, stride);

    final_kernel<<<1, 64, 0, stream>>>(s1, c1, s2, (float*)d_out, B, M, ptN, ptM);
}